// Round 17
// baseline (410.716 us; speedup 1.0000x reference)
//
#include <hip/hip_runtime.h>
#include <math.h>

#define BB 32
#define SS 2048
#define HH 1024
#define MT (BB*SS)      // 65536 rows

#define BM 256
#define BN 256
#define BK 32           // fp32 k per tile (hi/lo bf16 planes)
#define NT (HH/BK)      // 32 k-tiles
#define NCH (HH/BN)     // 4 n-chunks
#define THREADS 1024    // 16 waves (4m x 4n), per-wave 64x64 -> 4 waves/SIMD
// B_pre per (nch,kt) tile: 2 planes x 16 frags x 512 u16 = 16384 u16 (32KB)
#define BTILE 16384

typedef float  f32x4 __attribute__((ext_vector_type(4)));
typedef short  s16x8 __attribute__((ext_vector_type(8)));
typedef unsigned short u16;

// truncation split: x ~= hi + lo, |x - hi - lo| <= 2^-16 |x|
__device__ inline void split1(float x, u16& h, u16& l) {
    unsigned u = __float_as_uint(x);
    h = (u16)(u >> 16);
    float hf = __uint_as_float((u >> 16) << 16);
    l = (u16)(__float_as_uint(x - hf) >> 16);
}
__device__ inline void split8v(float4 v0, float4 v1, s16x8& h, s16x8& l) {
    float x[8] = {v0.x,v0.y,v0.z,v0.w,v1.x,v1.y,v1.z,v1.w};
    #pragma unroll
    for (int j = 0; j < 8; ++j) {
        u16 hh, ll; split1(x[j], hh, ll);
        h[j] = (short)hh; l[j] = (short)ll;
    }
}

// ---------------- Kernel 1: dec_proj[b][n] = dh[b]·Wa_w[:,n] + Wa_b[n] + Ua_b[n]
__global__ void dec_proj_kernel(const float* __restrict__ dh,
                                const float* __restrict__ Wa_w,
                                const float* __restrict__ Wa_b,
                                const float* __restrict__ Ua_b,
                                float* __restrict__ dec_proj) {
    __shared__ float sdh[HH];
    const int b   = blockIdx.x;
    const int nq  = blockIdx.y;           // 0..3
    const int tid = threadIdx.x;          // 256
    for (int i = tid; i < HH; i += 256) sdh[i] = dh[b*HH + i];
    __syncthreads();
    const int n = nq*256 + tid;
    float acc = Wa_b[n] + Ua_b[n];
    for (int k = 0; k < HH; ++k)
        acc = fmaf(sdh[k], Wa_w[(size_t)k*HH + n], acc);
    dec_proj[b*HH + n] = acc;
}

// ---------------- Kernel 2: Ua [K][N] -> B_pre frag-linear split-bf16 image
// (r5/r11-verified 16x16 image)
// B_pre[(nch*NT+kt)*16384 + plane*8192 + f*512 + (c*16+lr)*8 + j]
//   n = nch*256 + f*16 + lr ; k = kt*32 + c*8 + j ; plane 0=hi,1=lo
__global__ void transpose_convert_kernel(const float* __restrict__ Ua,
                                         u16* __restrict__ B_pre) {
    __shared__ u16 shh[64][72], shl[64][72];
    const int nb = blockIdx.x * 64, kb = blockIdx.y * 64;
    const int tid = threadIdx.x;          // 256
    const int kl = tid >> 4, nl4 = (tid & 15) * 4;
    #pragma unroll
    for (int q = 0; q < 4; ++q) {
        const int k = kl + q*16;
        float4 v = *(const float4*)&Ua[(size_t)(kb + k)*HH + nb + nl4];
        float x[4] = {v.x, v.y, v.z, v.w};
        #pragma unroll
        for (int j = 0; j < 4; ++j) {
            u16 hh, ll; split1(x[j], hh, ll);
            shh[k][nl4 + j] = hh; shl[k][nl4 + j] = ll;
        }
    }
    __syncthreads();
    const int nl = tid >> 3, kc8 = (tid & 7) * 8;
    #pragma unroll
    for (int q = 0; q < 2; ++q) {
        const int n = nb + nl + q*32;
        const int kglob = kb + kc8;
        s16x8 hv, lv;
        #pragma unroll
        for (int j = 0; j < 8; ++j) {
            hv[j] = (short)shh[kc8 + j][nl + q*32];
            lv[j] = (short)shl[kc8 + j][nl + q*32];
        }
        const int nchI = n >> 8, fI = (n >> 4) & 15, lrI = n & 15;
        const int ktI = kglob >> 5, cI = (kglob >> 3) & 3;
        const size_t base = (size_t)(nchI*NT + ktI) * BTILE;
        const size_t idxH = base + fI*512 + (cI*16 + lrI)*8;
        *(s16x8*)&B_pre[idxH]        = hv;
        *(s16x8*)&B_pre[idxH + 8192] = lv;
    }
}

// ---------------- Kernel 3: split-bf16 3-product MFMA GEMM, 16x16x32
// r16 structure, but B is read DIRECTLY from B_pre (L2) into registers each
// tile -- no B LDS at all. Rationale (r16 counters): per CU per tile,
// MFMA pipe = 3725 cyc and LDS stream = 320KB ~= 3765 cyc; measured 7460 =
// additive, so LDS traffic co-limits. Removing B's LDS write (32KB) and its
// 4x-amplified LDS reads (128KB) drops LDS to 160KB ~= 1880 cyc << MFMA.
// B reads stay perfectly coalesced (contiguous 1KB per wave per frag, the
// r7-verified direct path); L2-resident source; no extra VALU (pre-split).
// LDS now holds only the A double buffer -> same 1-barrier/tile ledger.
__global__ __launch_bounds__(THREADS, 4)
void gemm_fr_kernel(const float* __restrict__ A,        // enc [M, K] fp32
                    const u16* __restrict__ B_pre,      // frag-linear split image
                    const float* __restrict__ dec_proj, // [B, H] (biases folded)
                    const float* __restrict__ Va_w,     // [H]
                    float* __restrict__ partials)       // [M, 16]
{
    __shared__ __align__(16) u16 AhS[2][BM*BK];   // 2 x 16KB
    __shared__ __align__(16) u16 AlS[2][BM*BK];   // 2 x 16KB

    // XCD-chunked bijective swizzle: 1024 blocks, 128 per XCD;
    // nch fastest -> 4 concurrent blocks share each A panel via L2.
    const int bid = blockIdx.x;
    const int wg  = (bid & 7) * 128 + (bid >> 3);
    const int nch = wg & 3;
    const int mt  = wg >> 2;
    const int m0  = mt * BM, n0 = nch * BN;

    const int tid = threadIdx.x, lane = tid & 63, wid = tid >> 6;
    const int wm = wid >> 2, wn = wid & 3;    // 4 x 4 waves, per-wave 64x64
    const int lr = lane & 15, lk = lane >> 4;

    // A staging (write-linear map, r16-verified): tid -> frag=tid>>6,
    // chunk=(tid>>4)&3, row=tid&15; LDS write at tid*16B (0-conflict);
    // frag read at f*512 + lane*8 (1KB linear, 0-conflict).
    const float* Ab = A + (size_t)(m0 + (tid>>6)*16 + (tid&15))*HH + ((tid>>4)&3)*8;
    const int awoff = tid*8;   // u16 units
    // B direct-from-global base (r7-verified): wave reads its 4 frag pairs,
    // each a contiguous 1KB wave read at (wn*4+j)*512 + lane*8.
    const u16* Bt = B_pre + (size_t)nch*NT*BTILE + (wn*4)*512 + lane*8;

    f32x4 acc[4][4];
    #pragma unroll
    for (int i = 0; i < 4; ++i)
        #pragma unroll
        for (int j = 0; j < 4; ++j) acc[i][j] = (f32x4){0.f,0.f,0.f,0.f};

    s16x8  bh[4], bl[4];      // B frags, loaded from L2 once per tile (32 VGPR)
    float4 a0_, a1_;          // A staging regs (8 VGPR)

    auto loadA = [&](int kt) {
        const float* p = Ab + kt*BK;
        a0_ = *(const float4*)(p + 0);
        a1_ = *(const float4*)(p + 4);
    };
    auto writeA = [&](int db) {
        s16x8 h, l;
        split8v(a0_, a1_, h, l);
        *(s16x8*)&AhS[db][awoff] = h;
        *(s16x8*)&AlS[db][awoff] = l;
    };
    auto readB = [&](int kt) {
        const u16* p = Bt + (size_t)kt*BTILE;
        #pragma unroll
        for (int j = 0; j < 4; ++j) {
            bh[j] = *(const s16x8*)(p + j*512);
            bl[j] = *(const s16x8*)(p + 8192 + j*512);
        }
    };

    // prologue: stage A tile 0 into buf 0
    loadA(0);
    writeA(0);
    __syncthreads();
    loadA(1);   // A(1) regs held through iter 0

    for (int j = 0; j < NT; ++j) {
        const int cb = j & 1;
        const bool hn = (j + 1 < NT);

        readB(j);                       // 8 coalesced 1KB wave reads from L2
        #pragma unroll
        for (int f = 0; f < 4; ++f) {
            const int o = (wm*4 + f)*512 + lane*8;   // 1KB linear frag read
            const s16x8 ah = *(const s16x8*)&AhS[cb][o];
            const s16x8 al = *(const s16x8*)&AlS[cb][o];
            __builtin_amdgcn_s_setprio(1);
            #pragma unroll
            for (int q = 0; q < 4; ++q) {
                f32x4 c = acc[f][q];
                c = __builtin_amdgcn_mfma_f32_16x16x32_bf16(ah, bh[q], c, 0, 0, 0);
                c = __builtin_amdgcn_mfma_f32_16x16x32_bf16(ah, bl[q], c, 0, 0, 0);
                c = __builtin_amdgcn_mfma_f32_16x16x32_bf16(al, bh[q], c, 0, 0, 0);
                acc[f][q] = c;
            }
            __builtin_amdgcn_s_setprio(0);
        }
        // staging at END (r11/r16 proven order): writeA's wait targets loads
        // issued a full tile ago (~free); loadA(j+2) gets a full tile to land.
        if (hn) {
            writeA(cb ^ 1);
            loadA(j + 2 < NT ? j + 2 : j + 1);
        }
        __syncthreads();   // protects only the A double buffer now
    }

    // epilogue: rowsum over this wave's 64 n-cols of Va[n]*tanh(C+dp[n])
    // 16x16 C layout (verified): col=lane&15, row=(lane>>4)*4+reg
    const int bidx = m0 >> 11;            // batch index (2048 rows per batch)
    float dp[4], va[4];
    #pragma unroll
    for (int j = 0; j < 4; ++j) {
        const int n = n0 + wn*64 + j*16 + lr;
        dp[j] = dec_proj[bidx*HH + n];
        va[j] = Va_w[n];
    }
    #pragma unroll
    for (int f = 0; f < 4; ++f) {
        #pragma unroll
        for (int r = 0; r < 4; ++r) {
            float s = 0.f;
            #pragma unroll
            for (int j = 0; j < 4; ++j)
                s += va[j] * tanhf(acc[f][j][r] + dp[j]);
            s += __shfl_xor(s, 1, 64);
            s += __shfl_xor(s, 2, 64);
            s += __shfl_xor(s, 4, 64);
            s += __shfl_xor(s, 8, 64);
            if (lr == 0) {
                const int m = m0 + wm*64 + f*16 + lk*4 + r;
                partials[(size_t)m*16 + nch*4 + wn] = s;
            }
        }
    }
}

// ---------------- Kernel 4: sum 16 partials + Va_b, mask, softmax over S
__global__ void softmax_kernel(const float* __restrict__ partials,
                               const int* __restrict__ mask,
                               const float* __restrict__ vb_ptr,
                               float* __restrict__ out)
{
    const int b   = blockIdx.x;
    const int tid = threadIdx.x;   // 256, each handles 8 s-positions
    __shared__ float sred[8];
    const float vb = vb_ptr[0];
    float sc[8];
    float mymax = -INFINITY;
    #pragma unroll
    for (int i = 0; i < 8; ++i) {
        const int s = i*256 + tid;
        const float4* p = (const float4*)&partials[((size_t)b*SS + s)*16];
        const float4 x = p[0], y = p[1], z = p[2], w = p[3];
        float v = (((x.x+x.y)+(x.z+x.w)) + ((y.x+y.y)+(y.z+y.w)))
                + (((z.x+z.y)+(z.z+z.w)) + ((w.x+w.y)+(w.z+w.w))) + vb;
        if (mask[b*SS + s] == 0) v = -1e9f;
        sc[i] = v;
        mymax = fmaxf(mymax, v);
    }
    #pragma unroll
    for (int off = 1; off < 64; off <<= 1)
        mymax = fmaxf(mymax, __shfl_xor(mymax, off, 64));
    const int wave = tid >> 6, lane = tid & 63;
    if (lane == 0) sred[wave] = mymax;
    __syncthreads();
    const float bmax = fmaxf(fmaxf(sred[0], sred[1]), fmaxf(sred[2], sred[3]));
    float ex[8], mysum = 0.f;
    #pragma unroll
    for (int i = 0; i < 8; ++i) {
        ex[i] = __expf(sc[i] - bmax);
        mysum += ex[i];
    }
    #pragma unroll
    for (int off = 1; off < 64; off <<= 1)
        mysum += __shfl_xor(mysum, off, 64);
    if (lane == 0) sred[4 + wave] = mysum;
    __syncthreads();
    const float inv = 1.f / (sred[4] + sred[5] + sred[6] + sred[7]);
    #pragma unroll
    for (int i = 0; i < 8; ++i)
        out[(size_t)b*SS + i*256 + tid] = ex[i] * inv;
}

extern "C" void kernel_launch(void* const* d_in, const int* in_sizes, int n_in,
                              void* d_out, int out_size, void* d_ws, size_t ws_size,
                              hipStream_t stream) {
    const float* dh   = (const float*)d_in[0];
    const float* enc  = (const float*)d_in[1];
    const int*   mask = (const int*)d_in[2];
    const float* Wa_w = (const float*)d_in[3];
    const float* Wa_b = (const float*)d_in[4];
    const float* Ua_w = (const float*)d_in[5];
    const float* Ua_b = (const float*)d_in[6];
    const float* Va_w = (const float*)d_in[7];
    const float* Va_b = (const float*)d_in[8];
    float* out = (float*)d_out;

    float* dec_proj = (float*)d_ws;                       // [B,H]    128 KB
    float* partials = dec_proj + BB*HH;                   // [M,16]   4 MB
    u16*   B_pre    = (u16*)(partials + (size_t)MT*16);   // frag-linear, 4 MB

    dec_proj_kernel<<<dim3(BB, 4), 256, 0, stream>>>(dh, Wa_w, Wa_b, Ua_b, dec_proj);
    transpose_convert_kernel<<<dim3(HH/64, HH/64), 256, 0, stream>>>(Ua_w, B_pre);
    gemm_fr_kernel<<<(MT/BM)*NCH, THREADS, 0, stream>>>(enc, B_pre, dec_proj, Va_w, partials);
    softmax_kernel<<<BB, 256, 0, stream>>>(partials, mask, Va_b, out);
}

// Round 18
// 407.274 us; speedup vs baseline: 1.0085x; 1.0085x over previous
//
#include <hip/hip_runtime.h>
#include <math.h>

#define BB 32
#define SS 2048
#define HH 1024
#define MT (BB*SS)      // 65536 rows

#define BM 128
#define BN 256
#define BK 32           // fp32 k per tile (hi/lo bf16 planes)
#define NT (HH/BK)      // 32 k-tiles
#define NCH (HH/BN)     // 4 n-chunks
#define THREADS 512     // 8 waves (2m x 4n), per-wave 64x64; 2 blocks/CU
// B_pre per (nch,kt) tile: 2 planes x 16 frags x 512 u16 = 16384 u16 (32KB)
#define BTILE 16384

typedef float  f32x4 __attribute__((ext_vector_type(4)));
typedef short  s16x8 __attribute__((ext_vector_type(8)));
typedef unsigned short u16;

// truncation split: x ~= hi + lo, |x - hi - lo| <= 2^-16 |x|
__device__ inline void split1(float x, u16& h, u16& l) {
    unsigned u = __float_as_uint(x);
    h = (u16)(u >> 16);
    float hf = __uint_as_float((u >> 16) << 16);
    l = (u16)(__float_as_uint(x - hf) >> 16);
}
__device__ inline void split8v(float4 v0, float4 v1, s16x8& h, s16x8& l) {
    float x[8] = {v0.x,v0.y,v0.z,v0.w,v1.x,v1.y,v1.z,v1.w};
    #pragma unroll
    for (int j = 0; j < 8; ++j) {
        u16 hh, ll; split1(x[j], hh, ll);
        h[j] = (short)hh; l[j] = (short)ll;
    }
}

// ---------------- Kernel 1: dec_proj[b][n] = dh[b]·Wa_w[:,n] + Wa_b[n] + Ua_b[n]
__global__ void dec_proj_kernel(const float* __restrict__ dh,
                                const float* __restrict__ Wa_w,
                                const float* __restrict__ Wa_b,
                                const float* __restrict__ Ua_b,
                                float* __restrict__ dec_proj) {
    __shared__ float sdh[HH];
    const int b   = blockIdx.x;
    const int nq  = blockIdx.y;           // 0..3
    const int tid = threadIdx.x;          // 256
    for (int i = tid; i < HH; i += 256) sdh[i] = dh[b*HH + i];
    __syncthreads();
    const int n = nq*256 + tid;
    float acc = Wa_b[n] + Ua_b[n];
    for (int k = 0; k < HH; ++k)
        acc = fmaf(sdh[k], Wa_w[(size_t)k*HH + n], acc);
    dec_proj[b*HH + n] = acc;
}

// ---------------- Kernel 2: Ua [K][N] -> B_pre frag-linear split-bf16 image
// (r5/r11-verified 16x16 image)
// B_pre[(nch*NT+kt)*16384 + plane*8192 + f*512 + (c*16+lr)*8 + j]
//   n = nch*256 + f*16 + lr ; k = kt*32 + c*8 + j ; plane 0=hi,1=lo
__global__ void transpose_convert_kernel(const float* __restrict__ Ua,
                                         u16* __restrict__ B_pre) {
    __shared__ u16 shh[64][72], shl[64][72];
    const int nb = blockIdx.x * 64, kb = blockIdx.y * 64;
    const int tid = threadIdx.x;          // 256
    const int kl = tid >> 4, nl4 = (tid & 15) * 4;
    #pragma unroll
    for (int q = 0; q < 4; ++q) {
        const int k = kl + q*16;
        float4 v = *(const float4*)&Ua[(size_t)(kb + k)*HH + nb + nl4];
        float x[4] = {v.x, v.y, v.z, v.w};
        #pragma unroll
        for (int j = 0; j < 4; ++j) {
            u16 hh, ll; split1(x[j], hh, ll);
            shh[k][nl4 + j] = hh; shl[k][nl4 + j] = ll;
        }
    }
    __syncthreads();
    const int nl = tid >> 3, kc8 = (tid & 7) * 8;
    #pragma unroll
    for (int q = 0; q < 2; ++q) {
        const int n = nb + nl + q*32;
        const int kglob = kb + kc8;
        s16x8 hv, lv;
        #pragma unroll
        for (int j = 0; j < 8; ++j) {
            hv[j] = (short)shh[kc8 + j][nl + q*32];
            lv[j] = (short)shl[kc8 + j][nl + q*32];
        }
        const int nchI = n >> 8, fI = (n >> 4) & 15, lrI = n & 15;
        const int ktI = kglob >> 5, cI = (kglob >> 3) & 3;
        const size_t base = (size_t)(nchI*NT + ktI) * BTILE;
        const size_t idxH = base + fI*512 + (cI*16 + lrI)*8;
        *(s16x8*)&B_pre[idxH]        = hv;
        *(s16x8*)&B_pre[idxH + 8192] = lv;
    }
}

// ---------------- Kernel 3: split-bf16 3-product MFMA GEMM, 16x16x32
// r17 data paths EXACTLY, but block halved to BM=128 / 512 threads (8 waves):
// LDS 32KB + VGPR ~124 -> TWO blocks per CU, i.e. two INDEPENDENT barrier
// domains. Rationale (r15/r16/r17 all ~equal at MfmaUtil ~44-48%): the
// per-tile barrier phase-locks all waves of a block -- staging bursts and
// MFMA clusters alternate in lockstep, so the matrix pipe idles during
// staging and is 4x oversubscribed during MFMA. With 2 drifting blocks/CU,
// one block's MFMA covers the other's staging (m114 co-scheduling).
__global__ __launch_bounds__(THREADS, 4)
void gemm_fr_kernel(const float* __restrict__ A,        // enc [M, K] fp32
                    const u16* __restrict__ B_pre,      // frag-linear split image
                    const float* __restrict__ dec_proj, // [B, H] (biases folded)
                    const float* __restrict__ Va_w,     // [H]
                    float* __restrict__ partials)       // [M, 16]
{
    __shared__ __align__(16) u16 AhS[2][BM*BK];   // 2 x 8KB
    __shared__ __align__(16) u16 AlS[2][BM*BK];   // 2 x 8KB

    // XCD-chunked bijective swizzle: 2048 blocks, 256 per XCD;
    // nch fastest -> 4 consecutive blocks share each A panel via L2.
    const int bid = blockIdx.x;
    const int wg  = (bid & 7) * 256 + (bid >> 3);
    const int nch = wg & 3;
    const int mt  = wg >> 2;                  // 0..511
    const int m0  = mt * BM, n0 = nch * BN;

    const int tid = threadIdx.x, lane = tid & 63, wid = tid >> 6;
    const int wm = wid >> 2, wn = wid & 3;    // 2 x 4 waves, per-wave 64x64
    const int lr = lane & 15, lk = lane >> 4;

    // A staging (write-linear map, r16/r17-verified, scaled to BM=128):
    // tid -> frag=tid>>6 (0..7), chunk=(tid>>4)&3, row=tid&15;
    // LDS write at tid*16B (0-conflict); frag read at f*512+lane*8 (0-conflict).
    const float* Ab = A + (size_t)(m0 + (tid>>6)*16 + (tid&15))*HH + ((tid>>4)&3)*8;
    const int awoff = tid*8;   // u16 units
    // B direct-from-global base (r7/r17-verified): wave reads its 4 frag
    // pairs, each a contiguous 1KB wave read.
    const u16* Bt = B_pre + (size_t)nch*NT*BTILE + (wn*4)*512 + lane*8;

    f32x4 acc[4][4];
    #pragma unroll
    for (int i = 0; i < 4; ++i)
        #pragma unroll
        for (int j = 0; j < 4; ++j) acc[i][j] = (f32x4){0.f,0.f,0.f,0.f};

    s16x8  bh[4], bl[4];      // B frags, loaded from L2 once per tile (32 VGPR)
    float4 a0_, a1_;          // A staging regs (8 VGPR)

    auto loadA = [&](int kt) {
        const float* p = Ab + kt*BK;
        a0_ = *(const float4*)(p + 0);
        a1_ = *(const float4*)(p + 4);
    };
    auto writeA = [&](int db) {
        s16x8 h, l;
        split8v(a0_, a1_, h, l);
        *(s16x8*)&AhS[db][awoff] = h;
        *(s16x8*)&AlS[db][awoff] = l;
    };
    auto readB = [&](int kt) {
        const u16* p = Bt + (size_t)kt*BTILE;
        #pragma unroll
        for (int j = 0; j < 4; ++j) {
            bh[j] = *(const s16x8*)(p + j*512);
            bl[j] = *(const s16x8*)(p + 8192 + j*512);
        }
    };

    // prologue: stage A tile 0 into buf 0
    loadA(0);
    writeA(0);
    __syncthreads();
    loadA(1);   // A(1) regs held through iter 0

    for (int j = 0; j < NT; ++j) {
        const int cb = j & 1;
        const bool hn = (j + 1 < NT);

        readB(j);                       // 8 coalesced 1KB wave reads from L2
        #pragma unroll
        for (int f = 0; f < 4; ++f) {
            const int o = (wm*4 + f)*512 + lane*8;   // 1KB linear frag read
            const s16x8 ah = *(const s16x8*)&AhS[cb][o];
            const s16x8 al = *(const s16x8*)&AlS[cb][o];
            __builtin_amdgcn_s_setprio(1);
            #pragma unroll
            for (int q = 0; q < 4; ++q) {
                f32x4 c = acc[f][q];
                c = __builtin_amdgcn_mfma_f32_16x16x32_bf16(ah, bh[q], c, 0, 0, 0);
                c = __builtin_amdgcn_mfma_f32_16x16x32_bf16(ah, bl[q], c, 0, 0, 0);
                c = __builtin_amdgcn_mfma_f32_16x16x32_bf16(al, bh[q], c, 0, 0, 0);
                acc[f][q] = c;
            }
            __builtin_amdgcn_s_setprio(0);
        }
        // staging at END (r11/r16/r17 proven order)
        if (hn) {
            writeA(cb ^ 1);
            loadA(j + 2 < NT ? j + 2 : j + 1);
        }
        __syncthreads();   // protects only this block's A double buffer
    }

    // epilogue: rowsum over this wave's 64 n-cols of Va[n]*tanh(C+dp[n])
    // 16x16 C layout (verified): col=lane&15, row=(lane>>4)*4+reg
    const int bidx = m0 >> 11;            // batch index (2048 rows per batch)
    float dp[4], va[4];
    #pragma unroll
    for (int j = 0; j < 4; ++j) {
        const int n = n0 + wn*64 + j*16 + lr;
        dp[j] = dec_proj[bidx*HH + n];
        va[j] = Va_w[n];
    }
    #pragma unroll
    for (int f = 0; f < 4; ++f) {
        #pragma unroll
        for (int r = 0; r < 4; ++r) {
            float s = 0.f;
            #pragma unroll
            for (int j = 0; j < 4; ++j)
                s += va[j] * tanhf(acc[f][j][r] + dp[j]);
            s += __shfl_xor(s, 1, 64);
            s += __shfl_xor(s, 2, 64);
            s += __shfl_xor(s, 4, 64);
            s += __shfl_xor(s, 8, 64);
            if (lr == 0) {
                const int m = m0 + wm*64 + f*16 + lk*4 + r;
                partials[(size_t)m*16 + nch*4 + wn] = s;
            }
        }
    }
}

// ---------------- Kernel 4: sum 16 partials + Va_b, mask, softmax over S
__global__ void softmax_kernel(const float* __restrict__ partials,
                               const int* __restrict__ mask,
                               const float* __restrict__ vb_ptr,
                               float* __restrict__ out)
{
    const int b   = blockIdx.x;
    const int tid = threadIdx.x;   // 256, each handles 8 s-positions
    __shared__ float sred[8];
    const float vb = vb_ptr[0];
    float sc[8];
    float mymax = -INFINITY;
    #pragma unroll
    for (int i = 0; i < 8; ++i) {
        const int s = i*256 + tid;
        const float4* p = (const float4*)&partials[((size_t)b*SS + s)*16];
        const float4 x = p[0], y = p[1], z = p[2], w = p[3];
        float v = (((x.x+x.y)+(x.z+x.w)) + ((y.x+y.y)+(y.z+y.w)))
                + (((z.x+z.y)+(z.z+z.w)) + ((w.x+w.y)+(w.z+w.w))) + vb;
        if (mask[b*SS + s] == 0) v = -1e9f;
        sc[i] = v;
        mymax = fmaxf(mymax, v);
    }
    #pragma unroll
    for (int off = 1; off < 64; off <<= 1)
        mymax = fmaxf(mymax, __shfl_xor(mymax, off, 64));
    const int wave = tid >> 6, lane = tid & 63;
    if (lane == 0) sred[wave] = mymax;
    __syncthreads();
    const float bmax = fmaxf(fmaxf(sred[0], sred[1]), fmaxf(sred[2], sred[3]));
    float ex[8], mysum = 0.f;
    #pragma unroll
    for (int i = 0; i < 8; ++i) {
        ex[i] = __expf(sc[i] - bmax);
        mysum += ex[i];
    }
    #pragma unroll
    for (int off = 1; off < 64; off <<= 1)
        mysum += __shfl_xor(mysum, off, 64);
    if (lane == 0) sred[4 + wave] = mysum;
    __syncthreads();
    const float inv = 1.f / (sred[4] + sred[5] + sred[6] + sred[7]);
    #pragma unroll
    for (int i = 0; i < 8; ++i)
        out[(size_t)b*SS + i*256 + tid] = ex[i] * inv;
}

extern "C" void kernel_launch(void* const* d_in, const int* in_sizes, int n_in,
                              void* d_out, int out_size, void* d_ws, size_t ws_size,
                              hipStream_t stream) {
    const float* dh   = (const float*)d_in[0];
    const float* enc  = (const float*)d_in[1];
    const int*   mask = (const int*)d_in[2];
    const float* Wa_w = (const float*)d_in[3];
    const float* Wa_b = (const float*)d_in[4];
    const float* Ua_w = (const float*)d_in[5];
    const float* Ua_b = (const float*)d_in[6];
    const float* Va_w = (const float*)d_in[7];
    const float* Va_b = (const float*)d_in[8];
    float* out = (float*)d_out;

    float* dec_proj = (float*)d_ws;                       // [B,H]    128 KB
    float* partials = dec_proj + BB*HH;                   // [M,16]   4 MB
    u16*   B_pre    = (u16*)(partials + (size_t)MT*16);   // frag-linear, 4 MB

    dec_proj_kernel<<<dim3(BB, 4), 256, 0, stream>>>(dh, Wa_w, Wa_b, Ua_b, dec_proj);
    transpose_convert_kernel<<<dim3(HH/64, HH/64), 256, 0, stream>>>(Ua_w, B_pre);
    gemm_fr_kernel<<<(MT/BM)*NCH, THREADS, 0, stream>>>(enc, B_pre, dec_proj, Va_w, partials);
    softmax_kernel<<<BB, 256, 0, stream>>>(partials, mask, Va_b, out);
}

// Round 19
// 393.738 us; speedup vs baseline: 1.0431x; 1.0344x over previous
//
#include <hip/hip_runtime.h>
#include <math.h>

#define BB 32
#define SS 2048
#define HH 1024
#define MT (BB*SS)      // 65536 rows

#define BM 128
#define BN 256
#define BK 32           // fp32 k per tile (hi/lo bf16 planes)
#define NT (HH/BK)      // 32 k-tiles
#define NCH (HH/BN)     // 4 n-chunks
#define THREADS 512     // 8 waves (2m x 4n), per-wave 64x64; 2 blocks/CU
// B_pre per (nch,kt) tile: 2 planes x 16 frags x 512 u16 = 16384 u16 (32KB)
#define BTILE 16384

typedef float  f32x4 __attribute__((ext_vector_type(4)));
typedef short  s16x8 __attribute__((ext_vector_type(8)));
typedef unsigned short u16;

// truncation split: x ~= hi + lo, |x - hi - lo| <= 2^-16 |x|
__device__ inline void split1(float x, u16& h, u16& l) {
    unsigned u = __float_as_uint(x);
    h = (u16)(u >> 16);
    float hf = __uint_as_float((u >> 16) << 16);
    l = (u16)(__float_as_uint(x - hf) >> 16);
}
__device__ inline void split8v(float4 v0, float4 v1, s16x8& h, s16x8& l) {
    float x[8] = {v0.x,v0.y,v0.z,v0.w,v1.x,v1.y,v1.z,v1.w};
    #pragma unroll
    for (int j = 0; j < 8; ++j) {
        u16 hh, ll; split1(x[j], hh, ll);
        h[j] = (short)hh; l[j] = (short)ll;
    }
}

// ---------------- Kernel 1: dec_proj[b][n] = dh[b]·Wa_w[:,n] + Wa_b[n] + Ua_b[n]
__global__ void dec_proj_kernel(const float* __restrict__ dh,
                                const float* __restrict__ Wa_w,
                                const float* __restrict__ Wa_b,
                                const float* __restrict__ Ua_b,
                                float* __restrict__ dec_proj) {
    __shared__ float sdh[HH];
    const int b   = blockIdx.x;
    const int nq  = blockIdx.y;           // 0..3
    const int tid = threadIdx.x;          // 256
    for (int i = tid; i < HH; i += 256) sdh[i] = dh[b*HH + i];
    __syncthreads();
    const int n = nq*256 + tid;
    float acc = Wa_b[n] + Ua_b[n];
    for (int k = 0; k < HH; ++k)
        acc = fmaf(sdh[k], Wa_w[(size_t)k*HH + n], acc);
    dec_proj[b*HH + n] = acc;
}

// ---------------- Kernel 2: Ua [K][N] -> B_pre frag-linear split-bf16 image
// (r5/r11-verified 16x16 image)
// B_pre[(nch*NT+kt)*16384 + plane*8192 + f*512 + (c*16+lr)*8 + j]
//   n = nch*256 + f*16 + lr ; k = kt*32 + c*8 + j ; plane 0=hi,1=lo
__global__ void transpose_convert_kernel(const float* __restrict__ Ua,
                                         u16* __restrict__ B_pre) {
    __shared__ u16 shh[64][72], shl[64][72];
    const int nb = blockIdx.x * 64, kb = blockIdx.y * 64;
    const int tid = threadIdx.x;          // 256
    const int kl = tid >> 4, nl4 = (tid & 15) * 4;
    #pragma unroll
    for (int q = 0; q < 4; ++q) {
        const int k = kl + q*16;
        float4 v = *(const float4*)&Ua[(size_t)(kb + k)*HH + nb + nl4];
        float x[4] = {v.x, v.y, v.z, v.w};
        #pragma unroll
        for (int j = 0; j < 4; ++j) {
            u16 hh, ll; split1(x[j], hh, ll);
            shh[k][nl4 + j] = hh; shl[k][nl4 + j] = ll;
        }
    }
    __syncthreads();
    const int nl = tid >> 3, kc8 = (tid & 7) * 8;
    #pragma unroll
    for (int q = 0; q < 2; ++q) {
        const int n = nb + nl + q*32;
        const int kglob = kb + kc8;
        s16x8 hv, lv;
        #pragma unroll
        for (int j = 0; j < 8; ++j) {
            hv[j] = (short)shh[kc8 + j][nl + q*32];
            lv[j] = (short)shl[kc8 + j][nl + q*32];
        }
        const int nchI = n >> 8, fI = (n >> 4) & 15, lrI = n & 15;
        const int ktI = kglob >> 5, cI = (kglob >> 3) & 3;
        const size_t base = (size_t)(nchI*NT + ktI) * BTILE;
        const size_t idxH = base + fI*512 + (cI*16 + lrI)*8;
        *(s16x8*)&B_pre[idxH]        = hv;
        *(s16x8*)&B_pre[idxH + 8192] = lv;
    }
}

// ---------------- Kernel 3: split-bf16 3-product MFMA GEMM, 16x16x32
// r18 data paths EXACTLY; two changes, both on the sync axis:
// (1) __syncthreads -> {s_waitcnt lgkmcnt(0); s_barrier} (raw). The implicit
//     vmcnt(0) drain was the per-tile serializer: loadA(j+2) is issued just
//     before the barrier, so every wave ate a full HBM/L3 miss (~600-900cyc)
//     at the drain, every tile. Only the LDS A-buffer crosses the barrier;
//     A-reg/B-reg loads are wave-private -> compiler's counted vmcnt before
//     their USES is sufficient (T4: never vmcnt(0) in the loop).
// (2) readB(j+1) issued right after the last bh/bl use (register WAR = free)
//     -> B's L2 latency spans the tile tail + barrier instead of stalling
//     the first MFMA of the next tile. In-order vmcnt queue: writeA waits
//     vmcnt(8) (its a-regs are older than the 8 B loads); next tile's first
//     MFMA waits vmcnt(2) (keeps loadA(j+2) in flight). All counted, no drain.
// Ledger (1 barrier/tile, unchanged): tile j+1 writes buf cb only after the
// barrier ending tile j, where all reads of cb completed; lgkmcnt(0) before
// s_barrier publishes each wave's ds_writes.
__global__ __launch_bounds__(THREADS, 4)
void gemm_fr_kernel(const float* __restrict__ A,        // enc [M, K] fp32
                    const u16* __restrict__ B_pre,      // frag-linear split image
                    const float* __restrict__ dec_proj, // [B, H] (biases folded)
                    const float* __restrict__ Va_w,     // [H]
                    float* __restrict__ partials)       // [M, 16]
{
    __shared__ __align__(16) u16 AhS[2][BM*BK];   // 2 x 8KB
    __shared__ __align__(16) u16 AlS[2][BM*BK];   // 2 x 8KB

    // XCD-chunked bijective swizzle: 2048 blocks, 256 per XCD;
    // nch fastest -> 4 consecutive blocks share each A panel via L2.
    const int bid = blockIdx.x;
    const int wg  = (bid & 7) * 256 + (bid >> 3);
    const int nch = wg & 3;
    const int mt  = wg >> 2;                  // 0..511
    const int m0  = mt * BM, n0 = nch * BN;

    const int tid = threadIdx.x, lane = tid & 63, wid = tid >> 6;
    const int wm = wid >> 2, wn = wid & 3;    // 2 x 4 waves, per-wave 64x64
    const int lr = lane & 15, lk = lane >> 4;

    // A staging (write-linear map, r16/r17-verified, scaled to BM=128):
    // tid -> frag=tid>>6 (0..7), chunk=(tid>>4)&3, row=tid&15;
    // LDS write at tid*16B (0-conflict); frag read at f*512+lane*8 (0-conflict).
    const float* Ab = A + (size_t)(m0 + (tid>>6)*16 + (tid&15))*HH + ((tid>>4)&3)*8;
    const int awoff = tid*8;   // u16 units
    // B direct-from-global base (r7/r17-verified): wave reads its 4 frag
    // pairs, each a contiguous 1KB wave read.
    const u16* Bt = B_pre + (size_t)nch*NT*BTILE + (wn*4)*512 + lane*8;

    f32x4 acc[4][4];
    #pragma unroll
    for (int i = 0; i < 4; ++i)
        #pragma unroll
        for (int j = 0; j < 4; ++j) acc[i][j] = (f32x4){0.f,0.f,0.f,0.f};

    s16x8  bh[4], bl[4];      // B frags; prefetched one tile ahead (32 VGPR)
    float4 a0_, a1_;          // A staging regs (8 VGPR)

    auto loadA = [&](int kt) {
        const float* p = Ab + kt*BK;
        a0_ = *(const float4*)(p + 0);
        a1_ = *(const float4*)(p + 4);
    };
    auto writeA = [&](int db) {
        s16x8 h, l;
        split8v(a0_, a1_, h, l);
        *(s16x8*)&AhS[db][awoff] = h;
        *(s16x8*)&AlS[db][awoff] = l;
    };
    auto readB = [&](int kt) {
        const u16* p = Bt + (size_t)kt*BTILE;
        #pragma unroll
        for (int j = 0; j < 4; ++j) {
            bh[j] = *(const s16x8*)(p + j*512);
            bl[j] = *(const s16x8*)(p + 8192 + j*512);
        }
    };

    // prologue: stage A tile 0 into buf 0; B(0) into regs
    loadA(0);
    writeA(0);
    readB(0);
    __syncthreads();            // one full drain outside the loop is fine
    loadA(1);                   // A(1) regs held through iter 0

    for (int j = 0; j < NT; ++j) {
        const int cb = j & 1;
        const bool hn = (j + 1 < NT);

        #pragma unroll
        for (int f = 0; f < 4; ++f) {
            const int o = (wm*4 + f)*512 + lane*8;   // 1KB linear frag read
            const s16x8 ah = *(const s16x8*)&AhS[cb][o];
            const s16x8 al = *(const s16x8*)&AlS[cb][o];
            __builtin_amdgcn_s_setprio(1);
            #pragma unroll
            for (int q = 0; q < 4; ++q) {
                f32x4 c = acc[f][q];
                c = __builtin_amdgcn_mfma_f32_16x16x32_bf16(ah, bh[q], c, 0, 0, 0);
                c = __builtin_amdgcn_mfma_f32_16x16x32_bf16(ah, bl[q], c, 0, 0, 0);
                c = __builtin_amdgcn_mfma_f32_16x16x32_bf16(al, bh[q], c, 0, 0, 0);
                acc[f][q] = c;
            }
            __builtin_amdgcn_s_setprio(0);
        }
        // tail staging: B prefetch first (WAR on bh/bl is free), then A
        if (hn) {
            readB(j + 1);                          // spans tail+barrier -> hidden
            writeA(cb ^ 1);                        // waits vmcnt(8): a-regs old
            loadA(j + 2 < NT ? j + 2 : j + 1);     // stays in flight past barrier
        }
        // raw barrier: publish ds_writes only; NO vmcnt drain (T4)
        asm volatile("s_waitcnt lgkmcnt(0)" ::: "memory");
        __builtin_amdgcn_sched_barrier(0);
        __builtin_amdgcn_s_barrier();
        __builtin_amdgcn_sched_barrier(0);
    }

    // epilogue: rowsum over this wave's 64 n-cols of Va[n]*tanh(C+dp[n])
    // 16x16 C layout (verified): col=lane&15, row=(lane>>4)*4+reg
    const int bidx = m0 >> 11;            // batch index (2048 rows per batch)
    float dp[4], va[4];
    #pragma unroll
    for (int j = 0; j < 4; ++j) {
        const int n = n0 + wn*64 + j*16 + lr;
        dp[j] = dec_proj[bidx*HH + n];
        va[j] = Va_w[n];
    }
    #pragma unroll
    for (int f = 0; f < 4; ++f) {
        #pragma unroll
        for (int r = 0; r < 4; ++r) {
            float s = 0.f;
            #pragma unroll
            for (int j = 0; j < 4; ++j)
                s += va[j] * tanhf(acc[f][j][r] + dp[j]);
            s += __shfl_xor(s, 1, 64);
            s += __shfl_xor(s, 2, 64);
            s += __shfl_xor(s, 4, 64);
            s += __shfl_xor(s, 8, 64);
            if (lr == 0) {
                const int m = m0 + wm*64 + f*16 + lk*4 + r;
                partials[(size_t)m*16 + nch*4 + wn] = s;
            }
        }
    }
}

// ---------------- Kernel 4: sum 16 partials + Va_b, mask, softmax over S
__global__ void softmax_kernel(const float* __restrict__ partials,
                               const int* __restrict__ mask,
                               const float* __restrict__ vb_ptr,
                               float* __restrict__ out)
{
    const int b   = blockIdx.x;
    const int tid = threadIdx.x;   // 256, each handles 8 s-positions
    __shared__ float sred[8];
    const float vb = vb_ptr[0];
    float sc[8];
    float mymax = -INFINITY;
    #pragma unroll
    for (int i = 0; i < 8; ++i) {
        const int s = i*256 + tid;
        const float4* p = (const float4*)&partials[((size_t)b*SS + s)*16];
        const float4 x = p[0], y = p[1], z = p[2], w = p[3];
        float v = (((x.x+x.y)+(x.z+x.w)) + ((y.x+y.y)+(y.z+y.w)))
                + (((z.x+z.y)+(z.z+z.w)) + ((w.x+w.y)+(w.z+w.w))) + vb;
        if (mask[b*SS + s] == 0) v = -1e9f;
        sc[i] = v;
        mymax = fmaxf(mymax, v);
    }
    #pragma unroll
    for (int off = 1; off < 64; off <<= 1)
        mymax = fmaxf(mymax, __shfl_xor(mymax, off, 64));
    const int wave = tid >> 6, lane = tid & 63;
    if (lane == 0) sred[wave] = mymax;
    __syncthreads();
    const float bmax = fmaxf(fmaxf(sred[0], sred[1]), fmaxf(sred[2], sred[3]));
    float ex[8], mysum = 0.f;
    #pragma unroll
    for (int i = 0; i < 8; ++i) {
        ex[i] = __expf(sc[i] - bmax);
        mysum += ex[i];
    }
    #pragma unroll
    for (int off = 1; off < 64; off <<= 1)
        mysum += __shfl_xor(mysum, off, 64);
    if (lane == 0) sred[4 + wave] = mysum;
    __syncthreads();
    const float inv = 1.f / (sred[4] + sred[5] + sred[6] + sred[7]);
    #pragma unroll
    for (int i = 0; i < 8; ++i)
        out[(size_t)b*SS + i*256 + tid] = ex[i] * inv;
}

extern "C" void kernel_launch(void* const* d_in, const int* in_sizes, int n_in,
                              void* d_out, int out_size, void* d_ws, size_t ws_size,
                              hipStream_t stream) {
    const float* dh   = (const float*)d_in[0];
    const float* enc  = (const float*)d_in[1];
    const int*   mask = (const int*)d_in[2];
    const float* Wa_w = (const float*)d_in[3];
    const float* Wa_b = (const float*)d_in[4];
    const float* Ua_w = (const float*)d_in[5];
    const float* Ua_b = (const float*)d_in[6];
    const float* Va_w = (const float*)d_in[7];
    const float* Va_b = (const float*)d_in[8];
    float* out = (float*)d_out;

    float* dec_proj = (float*)d_ws;                       // [B,H]    128 KB
    float* partials = dec_proj + BB*HH;                   // [M,16]   4 MB
    u16*   B_pre    = (u16*)(partials + (size_t)MT*16);   // frag-linear, 4 MB

    dec_proj_kernel<<<dim3(BB, 4), 256, 0, stream>>>(dh, Wa_w, Wa_b, Ua_b, dec_proj);
    transpose_convert_kernel<<<dim3(HH/64, HH/64), 256, 0, stream>>>(Ua_w, B_pre);
    gemm_fr_kernel<<<(MT/BM)*NCH, THREADS, 0, stream>>>(enc, B_pre, dec_proj, Va_w, partials);
    softmax_kernel<<<BB, 256, 0, stream>>>(partials, mask, Va_b, out);
}